// Round 3
// baseline (22917.288 us; speedup 1.0000x reference)
//
#include <hip/hip_runtime.h>
#include <cstdint>

// Problem constants
#define Bsz 2048
#define Ssz 50
#define Esz 256
#define Hsz 512
#define Wsz 256
#define Lsz 50
#define Vsz 51

// ---------------- threefry2x32 (20 rounds), key words (k0,k1) ----------------
__host__ __device__ __forceinline__ void threefry2x32_hd(
    unsigned k0, unsigned k1, unsigned x0, unsigned x1,
    unsigned& o0, unsigned& o1) {
  unsigned ks2 = k0 ^ k1 ^ 0x1BD11BDAu;
  x0 += k0; x1 += k1;
#define TF_RND(r) { x0 += x1; x1 = (x1 << (r)) | (x1 >> (32 - (r))); x1 ^= x0; }
  TF_RND(13) TF_RND(15) TF_RND(26) TF_RND(6)
  x0 += k1; x1 += ks2 + 1u;
  TF_RND(17) TF_RND(29) TF_RND(16) TF_RND(24)
  x0 += ks2; x1 += k0 + 2u;
  TF_RND(13) TF_RND(15) TF_RND(26) TF_RND(6)
  x0 += k0; x1 += k1 + 3u;
  TF_RND(17) TF_RND(29) TF_RND(16) TF_RND(24)
  x0 += k1; x1 += ks2 + 4u;
  TF_RND(13) TF_RND(15) TF_RND(26) TF_RND(6)
  x0 += ks2; x1 += k0 + 5u;
#undef TF_RND
  o0 = x0; o1 = x1;
}

// ------- prep: WgT[k][j][g] = Whh[g*512+j][k]   (float4 per [k][j]) ---------
__global__ __launch_bounds__(256) void prep_wgt(const float* __restrict__ src,
                                                float* __restrict__ dst) {
  int idx = blockIdx.x * 256 + threadIdx.x;   // < 512*512
  int j = idx & 511, k = idx >> 9;
  float4 v;
  v.x = src[(size_t)(0 * 512 + j) * 512 + k];
  v.y = src[(size_t)(1 * 512 + j) * 512 + k];
  v.z = src[(size_t)(2 * 512 + j) * 512 + k];
  v.w = src[(size_t)(3 * 512 + j) * 512 + k];
  ((float4*)dst)[(size_t)k * 512 + j] = v;    // writes coalesced
}

// ------- prep: WtT[k][w] = Wsrc[w][k]   (scalar float, [k][w]) --------------
__global__ __launch_bounds__(256) void prep_wtT(const float* __restrict__ src,
                                                float* __restrict__ dst) {
  int idx = blockIdx.x * 256 + threadIdx.x;   // < 512*256
  int w = idx & 255, k = idx >> 8;
  dst[(size_t)k * 256 + w] = src[(size_t)w * Hsz + k];
}

// ---------------- prep: encInP[v][j][g] = emb[v].Wih[g*512+j] + bih + bhh ----
__global__ __launch_bounds__(256) void prep_encin(
    const float* __restrict__ emb, const float* __restrict__ Wih,
    const float* __restrict__ bih, const float* __restrict__ bhh,
    float* __restrict__ encInP) {
  int wid = blockIdx.x * 4 + (threadIdx.x >> 6);
  int lane = threadIdx.x & 63;
  if (wid >= Vsz * 2048) return;
  int v = wid >> 11, col = wid & 2047;
  float4 e = ((const float4*)emb)[v * 64 + lane];
  float4 w = ((const float4*)Wih)[col * 64 + lane];
  float d = e.x * w.x + e.y * w.y + e.z * w.z + e.w * w.w;
  for (int off = 32; off; off >>= 1) d += __shfl_xor(d, off);
  if (lane == 0) {
    int g = col >> 9, j = col & 511;
    encInP[(size_t)v * 2048 + j * 4 + g] = d + bih[col] + bhh[col];
  }
}

// ---------------- prep: dbiasP[j][g] = dec_bih + dec_bhh ----------------
__global__ __launch_bounds__(256) void prep_dbias(const float* __restrict__ a,
                                                  const float* __restrict__ b,
                                                  float* __restrict__ dst) {
  int col = blockIdx.x * 256 + threadIdx.x;  // < 2048
  int g = col >> 9, j = col & 511;
  dst[j * 4 + g] = a[col] + b[col];
}

// ---------------- gates: h^T streaming GEMM + LSTM cell (no LDS) ------------
// grid 512: 32 b-groups (64 b) x 16 j-groups (32 j). thread = 4b x 2j-quads.
// hT layout [k][b]; WgT layout [k][j][4]; cT/houtT layout [j][b].
// Optional fused blend1 (encoder): block covers 16 w x 64 b.
__global__ __launch_bounds__(256) void gates_fused(
    const float* __restrict__ hT, const float* __restrict__ WgT,
    const float* __restrict__ addtab, const int* __restrict__ input, int tstep,
    float* __restrict__ houtT, float* __restrict__ cT,
    const float* __restrict__ W1T, float* __restrict__ b1row) {
  const int t = threadIdx.x;
  const int tj = t & 15, tb = t >> 4;
  const int bgrp = blockIdx.x >> 4;   // 0..31
  const int jgrp = blockIdx.x & 15;   // 0..15
  const int b0 = bgrp * 64 + tb * 4;
  const int j0 = jgrp * 32 + tj * 2;

  // ---- fused blend1 (encoder only): w = jgrp*16+tj, 4 b rows ----
  if (b1row) {
    const int w = jgrp * 16 + tj;
    float a4[4] = {0.f, 0.f, 0.f, 0.f};
    const float* __restrict__ wp = W1T + w;
    const float* __restrict__ hp = hT + b0;
#pragma unroll 4
    for (int kk = 0; kk < Hsz; ++kk) {
      float wv = wp[(size_t)kk * 256];
      float4 hv = *(const float4*)(hp + (size_t)kk * 2048);
      a4[0] = fmaf(hv.x, wv, a4[0]);
      a4[1] = fmaf(hv.y, wv, a4[1]);
      a4[2] = fmaf(hv.z, wv, a4[2]);
      a4[3] = fmaf(hv.w, wv, a4[3]);
    }
#pragma unroll
    for (int i = 0; i < 4; ++i)
      b1row[(size_t)(b0 + i) * (Ssz * Wsz) + w] = a4[i];
  }

  // ---- main GEMM: acc[4 b][2 j-quads] ----
  const float4* __restrict__ Wr = (const float4*)WgT + j0;
  const float4* __restrict__ Hr = (const float4*)hT + (b0 >> 2);
  float4 acc[4][2];
#pragma unroll
  for (int i = 0; i < 4; ++i)
#pragma unroll
    for (int p = 0; p < 2; ++p) acc[i][p] = make_float4(0.f, 0.f, 0.f, 0.f);

#pragma unroll 8
  for (int kk = 0; kk < Hsz; ++kk) {
    float4 w0 = Wr[(size_t)kk * 512];
    float4 w1 = Wr[(size_t)kk * 512 + 1];
    float4 hv = Hr[(size_t)kk * 512];
#define FMA8(i, s)                                                        \
  acc[i][0].x = fmaf(s, w0.x, acc[i][0].x);                               \
  acc[i][0].y = fmaf(s, w0.y, acc[i][0].y);                               \
  acc[i][0].z = fmaf(s, w0.z, acc[i][0].z);                               \
  acc[i][0].w = fmaf(s, w0.w, acc[i][0].w);                               \
  acc[i][1].x = fmaf(s, w1.x, acc[i][1].x);                               \
  acc[i][1].y = fmaf(s, w1.y, acc[i][1].y);                               \
  acc[i][1].z = fmaf(s, w1.z, acc[i][1].z);                               \
  acc[i][1].w = fmaf(s, w1.w, acc[i][1].w);
    FMA8(0, hv.x) FMA8(1, hv.y) FMA8(2, hv.z) FMA8(3, hv.w)
#undef FMA8
  }

  // ---- epilogue: add input-proj/bias, LSTM nonlinearity, write cT/hT ----
  size_t tokoff[4];
#pragma unroll
  for (int i = 0; i < 4; ++i)
    tokoff[i] = (input ? (size_t)input[(size_t)(b0 + i) * Ssz + tstep] : 0) * 512;

#pragma unroll
  for (int p = 0; p < 2; ++p) {
    const int j = j0 + p;
    float4 cv = *(float4*)(cT + (size_t)j * 2048 + b0);
    float4 hv;
    float* cvp = &cv.x;
    float* hvp = &hv.x;
#pragma unroll
    for (int i = 0; i < 4; ++i) {
      float4 av = ((const float4*)addtab)[tokoff[i] + j];
      float4 a = acc[i][p];
      float gi = a.x + av.x;
      float gf = a.y + av.y;
      float gg = a.z + av.z;
      float go = a.w + av.w;
      float si = 1.0f / (1.0f + expf(-gi));
      float sf = 1.0f / (1.0f + expf(-gf));
      float sg = tanhf(gg);
      float so = 1.0f / (1.0f + expf(-go));
      float cn = sf * cvp[i] + si * sg;
      cvp[i] = cn;
      hvp[i] = so * tanhf(cn);
    }
    *(float4*)(cT + (size_t)j * 2048 + b0) = cv;
    *(float4*)(houtT + (size_t)j * 2048 + b0) = hv;
  }
}

// ---------------- standalone blend1 row (encoder tail, h_50 -> row 49) -------
__global__ __launch_bounds__(256) void blend1_row(
    const float* __restrict__ hT, const float* __restrict__ W1T,
    float* __restrict__ b1) {
  const int w = threadIdx.x;
  const int b0 = blockIdx.x * 4;
  float a4[4] = {0.f, 0.f, 0.f, 0.f};
#pragma unroll 4
  for (int kk = 0; kk < Hsz; ++kk) {
    float wv = W1T[(size_t)kk * 256 + w];
    float4 hv = *(const float4*)(hT + (size_t)kk * 2048 + b0);
    a4[0] = fmaf(hv.x, wv, a4[0]);
    a4[1] = fmaf(hv.y, wv, a4[1]);
    a4[2] = fmaf(hv.z, wv, a4[2]);
    a4[3] = fmaf(hv.w, wv, a4[3]);
  }
#pragma unroll
  for (int i = 0; i < 4; ++i)
    b1[((size_t)(b0 + i) * Ssz + (Ssz - 1)) * Wsz + w] = a4[i];
}

// ---------------- decoder fused: blend2 + scores + log_softmax + sample ------
// grid 512: 4 b per block.
__global__ __launch_bounds__(256) void scores_fused(
    const float* __restrict__ hdT, const float* __restrict__ W2T,
    const float* __restrict__ b1, const float* __restrict__ vt,
    unsigned long long* __restrict__ mask,
    float* __restrict__ probs, float* __restrict__ tour,
    int stepk, unsigned kA, unsigned kB) {
  __shared__ float b2s[4][256];
  __shared__ float vts[256];
  __shared__ float sc[4][64];
  const int t = threadIdx.x;
  const int b0 = blockIdx.x * 4;

  // ---- phase A: blend2[b][w] for 4 b, thread <-> w ----
  {
    float a4[4] = {0.f, 0.f, 0.f, 0.f};
#pragma unroll 4
    for (int kk = 0; kk < Hsz; ++kk) {
      float wv = W2T[(size_t)kk * 256 + t];
      float4 hv = *(const float4*)(hdT + (size_t)kk * 2048 + b0);
      a4[0] = fmaf(hv.x, wv, a4[0]);
      a4[1] = fmaf(hv.y, wv, a4[1]);
      a4[2] = fmaf(hv.z, wv, a4[2]);
      a4[3] = fmaf(hv.w, wv, a4[3]);
    }
#pragma unroll
    for (int i = 0; i < 4; ++i) b2s[i][t] = a4[i];
    vts[t] = vt[t];
  }
  __syncthreads();

  // ---- phase B: scores rows (4 b x 50 s), one wave per row ----
  const int wave = t >> 6, lane = t & 63;
  for (int r = wave; r < 4 * Ssz; r += 4) {
    const int b = r / Ssz, s = r - b * Ssz;
    const float4* row = (const float4*)(b1 + ((size_t)(b0 + b) * Ssz + s) * Wsz);
    float4 rv = row[lane];
    float4 bv = *(const float4*)&b2s[b][lane * 4];
    float4 vv = *(const float4*)&vts[lane * 4];
    float v = vv.x * tanhf(rv.x + bv.x) + vv.y * tanhf(rv.y + bv.y) +
              vv.z * tanhf(rv.z + bv.z) + vv.w * tanhf(rv.w + bv.w);
    for (int off = 32; off; off >>= 1) v += __shfl_xor(v, off);
    if (lane == 0) sc[b][s] = v;
  }
  __syncthreads();

  // ---- phase C: mask, log_softmax, gumbel sample, mask update ----
  for (int bb = wave; bb < 4; bb += 4) {
    const int gb = b0 + bb;
    unsigned long long m = mask[gb];
    float x = (lane < Ssz) ? sc[bb][lane] : -INFINITY;
    if (lane < Ssz && ((m >> lane) & 1ull)) x = -100000.0f;
    float mv = x;
    for (int off = 32; off; off >>= 1) mv = fmaxf(mv, __shfl_xor(mv, off));
    float sh = x - mv;
    float e = (lane < Ssz) ? expf(sh) : 0.f;
    float ssum = e;
    for (int off = 32; off; off >>= 1) ssum += __shfl_xor(ssum, off);
    float lg = logf(ssum);
    float logp = sh - lg;
    if (lane < Ssz) probs[(size_t)gb * (Lsz * Ssz) + stepk * Ssz + lane] = logp;

    float val = -INFINITY;
    if (lane < Ssz) {
      unsigned j = (unsigned)(gb * Ssz + lane);
      unsigned o0, o1;
      threefry2x32_hd(kA, kB, 0u, j, o0, o1);
      unsigned bits = o0 ^ o1;
      float f = __uint_as_float((bits >> 9) | 0x3F800000u) - 1.0f;
      float u = fmaxf(1.17549435e-38f, f + 1.17549435e-38f);
      val = logp - logf(-logf(u));
    }
    int idx = lane;
    for (int off = 32; off; off >>= 1) {
      float ov = __shfl_xor(val, off);
      int oi = __shfl_xor(idx, off);
      if (ov > val || (ov == val && oi < idx)) { val = ov; idx = oi; }
    }
    if (lane == 0) {
      tour[(size_t)gb * Lsz + stepk] = (float)idx;
      mask[gb] = m | (1ull << idx);
    }
  }
}

extern "C" void kernel_launch(void* const* d_in, const int* in_sizes, int n_in,
                              void* d_out, int out_size, void* d_ws, size_t ws_size,
                              hipStream_t stream) {
  (void)in_sizes; (void)n_in; (void)out_size; (void)ws_size;
  const int*   input = (const int*)d_in[0];
  const float* emb   = (const float*)d_in[1];
  const float* eWih  = (const float*)d_in[2];
  const float* eWhh  = (const float*)d_in[3];
  const float* ebih  = (const float*)d_in[4];
  const float* ebhh  = (const float*)d_in[5];
  /* d_in[6] dec_Wih unused: decoder input is always zero */
  const float* dWhh  = (const float*)d_in[7];
  const float* dbih  = (const float*)d_in[8];
  const float* dbhh  = (const float*)d_in[9];
  const float* W1    = (const float*)d_in[10];
  const float* W2    = (const float*)d_in[11];
  const float* vt    = (const float*)d_in[12];
  float* outF = (float*)d_out;

  float* wsf = (float*)d_ws;
  size_t o = 0;
  float* WgE   = wsf + o; o += (size_t)512 * 512 * 4;   // 4 MB
  float* WgD   = wsf + o; o += (size_t)512 * 512 * 4;   // 4 MB
  float* encInP = wsf + o; o += (size_t)Vsz * 2048;
  float* dbiasP = wsf + o; o += 2048;
  float* W1T  = wsf + o; o += (size_t)512 * 256;
  float* W2T  = wsf + o; o += (size_t)512 * 256;
  float* hTa  = wsf + o; o += (size_t)Hsz * Bsz;
  float* hTb  = wsf + o; o += (size_t)Hsz * Bsz;
  float* cET  = wsf + o; o += (size_t)Hsz * Bsz;
  float* hdTa = wsf + o; o += (size_t)Hsz * Bsz;
  float* hdTb = wsf + o; o += (size_t)Hsz * Bsz;
  float* cDT  = wsf + o; o += (size_t)Hsz * Bsz;
  float* b1   = wsf + o; o += (size_t)Bsz * Ssz * Wsz;
  unsigned long long* maskp = (unsigned long long*)(wsf + o); o += Bsz * 2;

  hipMemsetAsync(hTa, 0, (size_t)Hsz * Bsz * 4, stream);
  hipMemsetAsync(cET, 0, (size_t)Hsz * Bsz * 4, stream);
  hipMemsetAsync(hdTa, 0, (size_t)Hsz * Bsz * 4, stream);
  hipMemsetAsync(maskp, 0, (size_t)Bsz * 8, stream);

  prep_wgt<<<1024, 256, 0, stream>>>(eWhh, WgE);
  prep_wgt<<<1024, 256, 0, stream>>>(dWhh, WgD);
  prep_encin<<<(Vsz * 2048) / 4, 256, 0, stream>>>(emb, eWih, ebih, ebhh, encInP);
  prep_dbias<<<8, 256, 0, stream>>>(dbih, dbhh, dbiasP);
  prep_wtT<<<512, 256, 0, stream>>>(W1, W1T);
  prep_wtT<<<512, 256, 0, stream>>>(W2, W2T);

  // host-side: step keys = jax.random.split(jax.random.key(42), 50)
  unsigned kAh[Lsz], kBh[Lsz];
  for (int k = 0; k < Lsz; ++k)
    threefry2x32_hd(0u, 42u, 0u, (unsigned)k, kAh[k], kBh[k]);

  // encoder: step t computes h_{t+1}; fused blend1 handles hin = h_t (row t-1)
  float* hr = hTa; float* hw = hTb;
  for (int t = 0; t < Ssz; ++t) {
    float* b1row = (t >= 1) ? (b1 + (size_t)(t - 1) * Wsz) : nullptr;
    gates_fused<<<512, 256, 0, stream>>>(hr, WgE, encInP, input, t, hw, cET,
                                         W1T, b1row);
    float* tp = hr; hr = hw; hw = tp;
  }
  blend1_row<<<512, 256, 0, stream>>>(hr, W1T, b1);  // h_50 -> row 49

  // decoder init: c0 = last encoder h (same [k][b] layout), h0 = 0
  hipMemcpyAsync(cDT, hr, (size_t)Hsz * Bsz * 4, hipMemcpyDeviceToDevice, stream);

  float* dr = hdTa; float* dw = hdTb;
  for (int k = 0; k < Lsz; ++k) {
    gates_fused<<<512, 256, 0, stream>>>(dr, WgD, dbiasP, nullptr, 0, dw, cDT,
                                         nullptr, nullptr);
    scores_fused<<<512, 256, 0, stream>>>(dw, W2T, b1, vt, maskp, outF,
                                          outF + (size_t)Bsz * Lsz * Ssz,
                                          k, kAh[k], kBh[k]);
    float* tp = dr; dr = dw; dw = tp;
  }
}

// Round 4
// 22227.835 us; speedup vs baseline: 1.0310x; 1.0310x over previous
//
#include <hip/hip_runtime.h>
#include <cstdint>

// Problem constants
#define Bsz 2048
#define Ssz 50
#define Esz 256
#define Hsz 512
#define Wsz 256
#define Lsz 50
#define Vsz 51

// ---------------- threefry2x32 (20 rounds), key words (k0,k1) ----------------
__host__ __device__ __forceinline__ void threefry2x32_hd(
    unsigned k0, unsigned k1, unsigned x0, unsigned x1,
    unsigned& o0, unsigned& o1) {
  unsigned ks2 = k0 ^ k1 ^ 0x1BD11BDAu;
  x0 += k0; x1 += k1;
#define TF_RND(r) { x0 += x1; x1 = (x1 << (r)) | (x1 >> (32 - (r))); x1 ^= x0; }
  TF_RND(13) TF_RND(15) TF_RND(26) TF_RND(6)
  x0 += k1; x1 += ks2 + 1u;
  TF_RND(17) TF_RND(29) TF_RND(16) TF_RND(24)
  x0 += ks2; x1 += k0 + 2u;
  TF_RND(13) TF_RND(15) TF_RND(26) TF_RND(6)
  x0 += k0; x1 += k1 + 3u;
  TF_RND(17) TF_RND(29) TF_RND(16) TF_RND(24)
  x0 += k1; x1 += ks2 + 4u;
  TF_RND(13) TF_RND(15) TF_RND(26) TF_RND(6)
  x0 += ks2; x1 += k0 + 5u;
#undef TF_RND
  o0 = x0; o1 = x1;
}

// ------- prep: WgT[k][j][g] = Whh[g*512+j][k]   (float4 per [k][j]) ---------
__global__ __launch_bounds__(256) void prep_wgt(const float* __restrict__ src,
                                                float* __restrict__ dst) {
  int idx = blockIdx.x * 256 + threadIdx.x;   // < 512*512
  int j = idx & 511, k = idx >> 9;
  float4 v;
  v.x = src[(size_t)(0 * 512 + j) * 512 + k];
  v.y = src[(size_t)(1 * 512 + j) * 512 + k];
  v.z = src[(size_t)(2 * 512 + j) * 512 + k];
  v.w = src[(size_t)(3 * 512 + j) * 512 + k];
  ((float4*)dst)[(size_t)k * 512 + j] = v;    // writes coalesced
}

// ------- prep: WtT[k][w] = Wsrc[w][k]   (scalar float, [k][w]) --------------
__global__ __launch_bounds__(256) void prep_wtT(const float* __restrict__ src,
                                                float* __restrict__ dst) {
  int idx = blockIdx.x * 256 + threadIdx.x;   // < 512*256
  int w = idx & 255, k = idx >> 8;
  dst[(size_t)k * 256 + w] = src[(size_t)w * Hsz + k];
}

// ---------------- prep: encInP[v][j][g] = emb[v].Wih[g*512+j] + bih + bhh ----
__global__ __launch_bounds__(256) void prep_encin(
    const float* __restrict__ emb, const float* __restrict__ Wih,
    const float* __restrict__ bih, const float* __restrict__ bhh,
    float* __restrict__ encInP) {
  int wid = blockIdx.x * 4 + (threadIdx.x >> 6);
  int lane = threadIdx.x & 63;
  if (wid >= Vsz * 2048) return;
  int v = wid >> 11, col = wid & 2047;
  float4 e = ((const float4*)emb)[v * 64 + lane];
  float4 w = ((const float4*)Wih)[col * 64 + lane];
  float d = e.x * w.x + e.y * w.y + e.z * w.z + e.w * w.w;
  for (int off = 32; off; off >>= 1) d += __shfl_xor(d, off);
  if (lane == 0) {
    int g = col >> 9, j = col & 511;
    encInP[(size_t)v * 2048 + j * 4 + g] = d + bih[col] + bhh[col];
  }
}

// ---------------- prep: dbiasP[j][g] = dec_bih + dec_bhh ----------------
__global__ __launch_bounds__(256) void prep_dbias(const float* __restrict__ a,
                                                  const float* __restrict__ b,
                                                  float* __restrict__ dst) {
  int col = blockIdx.x * 256 + threadIdx.x;  // < 2048
  int g = col >> 9, j = col & 511;
  dst[j * 4 + g] = a[col] + b[col];
}

// ---------------- gates: h^T streaming GEMM + LSTM cell (no LDS) ------------
// grid 1024 (4 blocks/CU, 16 waves/CU): 32 bgrp (64 b) x 32 jgrp (16 j).
// thread = 4 b x 1 j-quad: per k = 1x256B W read + 1x64B h read + 16 FMA.
// hT layout [k][b]; WgT layout [k][j][4gates]; cT/houtT layout [j][b].
// XCD swizzle: each XCD's 128 blocks share 4 bgrps (h L2-resident).
__global__ __launch_bounds__(256, 4) void gates_fused(
    const float* __restrict__ hT, const float* __restrict__ WgT,
    const float* __restrict__ addtab, const int* __restrict__ input, int tstep,
    float* __restrict__ houtT, float* __restrict__ cT,
    const float* __restrict__ W1T, float* __restrict__ b1row) {
  const int t = threadIdx.x;
  const int bid = blockIdx.x;
  const int xcd = bid & 7, local = bid >> 3;   // local 0..127
  const int bgrp = xcd * 4 + (local & 3);      // 0..31
  const int jgrp = local >> 2;                 // 0..31
  const int tj = t & 15, tb = t >> 4;
  const int b0 = bgrp * 64 + tb * 4;
  const int j0 = jgrp * 16 + tj;               // hidden index j, 0..511

  // ---- fused blend1 (encoder steps >= 1): 8 w x 64 b per block ----
  if (b1row) {
    const int w = jgrp * 8 + (t & 7);
    const int bb = b0 - tb * 4 + (t >> 3) * 2;  // bgrp*64 + (t>>3)*2
    float a0 = 0.f, a1 = 0.f;
    const float* __restrict__ wp = W1T + w;
    const float* __restrict__ hp = hT + bb;
#pragma unroll 8
    for (int kk = 0; kk < Hsz; ++kk) {
      float wv = wp[(size_t)kk * 256];
      float2 hv = *(const float2*)(hp + (size_t)kk * 2048);
      a0 = fmaf(hv.x, wv, a0);
      a1 = fmaf(hv.y, wv, a1);
    }
    b1row[(size_t)bb * (Ssz * Wsz) + w] = a0;
    b1row[(size_t)(bb + 1) * (Ssz * Wsz) + w] = a1;
  }

  // ---- main GEMM: acc[4 b] (float4 = 4 gates of column j0) ----
  const float4* __restrict__ Wr = (const float4*)WgT + j0;
  const float4* __restrict__ Hr = (const float4*)hT + (b0 >> 2);
  float4 acc[4];
#pragma unroll
  for (int i = 0; i < 4; ++i) acc[i] = make_float4(0.f, 0.f, 0.f, 0.f);

#pragma unroll 8
  for (int kk = 0; kk < Hsz; ++kk) {
    float4 w = Wr[(size_t)kk * 512];
    float4 hv = Hr[(size_t)kk * 512];
#define FMA4G(i, s)                                           \
  acc[i].x = fmaf(s, w.x, acc[i].x);                          \
  acc[i].y = fmaf(s, w.y, acc[i].y);                          \
  acc[i].z = fmaf(s, w.z, acc[i].z);                          \
  acc[i].w = fmaf(s, w.w, acc[i].w);
    FMA4G(0, hv.x) FMA4G(1, hv.y) FMA4G(2, hv.z) FMA4G(3, hv.w)
#undef FMA4G
  }

  // ---- epilogue: add input-proj/bias, LSTM nonlinearity, write cT/hT ----
  size_t tokoff[4];
#pragma unroll
  for (int i = 0; i < 4; ++i)
    tokoff[i] = (input ? (size_t)input[(size_t)(b0 + i) * Ssz + tstep] : 0) * 512;

  float4 cv = *(float4*)(cT + (size_t)j0 * 2048 + b0);
  float4 hv;
  float* cvp = &cv.x;
  float* hvp = &hv.x;
#pragma unroll
  for (int i = 0; i < 4; ++i) {
    float4 av = ((const float4*)addtab)[tokoff[i] + j0];
    float4 a = acc[i];
    float gi = a.x + av.x;
    float gf = a.y + av.y;
    float gg = a.z + av.z;
    float go = a.w + av.w;
    float si = 1.0f / (1.0f + expf(-gi));
    float sf = 1.0f / (1.0f + expf(-gf));
    float sg = tanhf(gg);
    float so = 1.0f / (1.0f + expf(-go));
    float cn = sf * cvp[i] + si * sg;
    cvp[i] = cn;
    hvp[i] = so * tanhf(cn);
  }
  *(float4*)(cT + (size_t)j0 * 2048 + b0) = cv;
  *(float4*)(houtT + (size_t)j0 * 2048 + b0) = hv;
}

// ---------------- standalone blend1 row (encoder tail, h_50 -> row 49) -------
__global__ __launch_bounds__(256) void blend1_row(
    const float* __restrict__ hT, const float* __restrict__ W1T,
    float* __restrict__ b1) {
  const int w = threadIdx.x;
  const int b0 = blockIdx.x * 4;
  float a4[4] = {0.f, 0.f, 0.f, 0.f};
#pragma unroll 4
  for (int kk = 0; kk < Hsz; ++kk) {
    float wv = W1T[(size_t)kk * 256 + w];
    float4 hv = *(const float4*)(hT + (size_t)kk * 2048 + b0);
    a4[0] = fmaf(hv.x, wv, a4[0]);
    a4[1] = fmaf(hv.y, wv, a4[1]);
    a4[2] = fmaf(hv.z, wv, a4[2]);
    a4[3] = fmaf(hv.w, wv, a4[3]);
  }
#pragma unroll
  for (int i = 0; i < 4; ++i)
    b1[((size_t)(b0 + i) * Ssz + (Ssz - 1)) * Wsz + w] = a4[i];
}

// ---------------- decoder fused: blend2 + scores + log_softmax + sample ------
// grid 1024 (4 blocks/CU): 2 b per block.
__global__ __launch_bounds__(256, 4) void scores_fused(
    const float* __restrict__ hdT, const float* __restrict__ W2T,
    const float* __restrict__ b1, const float* __restrict__ vt,
    unsigned long long* __restrict__ mask,
    float* __restrict__ probs, float* __restrict__ tour,
    int stepk, unsigned kA, unsigned kB) {
  __shared__ float b2s[2][256];
  __shared__ float vts[256];
  __shared__ float sc[2][64];
  const int t = threadIdx.x;
  const int b0 = blockIdx.x * 2;

  // ---- phase A: blend2[b][w] for 2 b, thread <-> w ----
  {
    float a0 = 0.f, a1 = 0.f;
#pragma unroll 8
    for (int kk = 0; kk < Hsz; ++kk) {
      float wv = W2T[(size_t)kk * 256 + t];
      float2 hv = *(const float2*)(hdT + (size_t)kk * 2048 + b0);
      a0 = fmaf(hv.x, wv, a0);
      a1 = fmaf(hv.y, wv, a1);
    }
    b2s[0][t] = a0;
    b2s[1][t] = a1;
    vts[t] = vt[t];
  }
  __syncthreads();

  // ---- phase B: scores rows (2 b x 50 s), one wave per row ----
  const int wave = t >> 6, lane = t & 63;
  for (int r = wave; r < 2 * Ssz; r += 4) {
    const int b = r / Ssz, s = r - b * Ssz;
    const float4* row = (const float4*)(b1 + ((size_t)(b0 + b) * Ssz + s) * Wsz);
    float4 rv = row[lane];
    float4 bv = *(const float4*)&b2s[b][lane * 4];
    float4 vv = *(const float4*)&vts[lane * 4];
    float v = vv.x * tanhf(rv.x + bv.x) + vv.y * tanhf(rv.y + bv.y) +
              vv.z * tanhf(rv.z + bv.z) + vv.w * tanhf(rv.w + bv.w);
    for (int off = 32; off; off >>= 1) v += __shfl_xor(v, off);
    if (lane == 0) sc[b][s] = v;
  }
  __syncthreads();

  // ---- phase C: mask, log_softmax, gumbel sample, mask update ----
  if (wave < 2) {
    const int gb = b0 + wave;
    unsigned long long m = mask[gb];
    float x = (lane < Ssz) ? sc[wave][lane] : -INFINITY;
    if (lane < Ssz && ((m >> lane) & 1ull)) x = -100000.0f;
    float mv = x;
    for (int off = 32; off; off >>= 1) mv = fmaxf(mv, __shfl_xor(mv, off));
    float sh = x - mv;
    float e = (lane < Ssz) ? expf(sh) : 0.f;
    float ssum = e;
    for (int off = 32; off; off >>= 1) ssum += __shfl_xor(ssum, off);
    float lg = logf(ssum);
    float logp = sh - lg;
    if (lane < Ssz) probs[(size_t)gb * (Lsz * Ssz) + stepk * Ssz + lane] = logp;

    float val = -INFINITY;
    if (lane < Ssz) {
      unsigned j = (unsigned)(gb * Ssz + lane);
      unsigned o0, o1;
      threefry2x32_hd(kA, kB, 0u, j, o0, o1);
      unsigned bits = o0 ^ o1;
      float f = __uint_as_float((bits >> 9) | 0x3F800000u) - 1.0f;
      float u = fmaxf(1.17549435e-38f, f + 1.17549435e-38f);
      val = logp - logf(-logf(u));
    }
    int idx = lane;
    for (int off = 32; off; off >>= 1) {
      float ov = __shfl_xor(val, off);
      int oi = __shfl_xor(idx, off);
      if (ov > val || (ov == val && oi < idx)) { val = ov; idx = oi; }
    }
    if (lane == 0) {
      tour[(size_t)gb * Lsz + stepk] = (float)idx;
      mask[gb] = m | (1ull << idx);
    }
  }
}

extern "C" void kernel_launch(void* const* d_in, const int* in_sizes, int n_in,
                              void* d_out, int out_size, void* d_ws, size_t ws_size,
                              hipStream_t stream) {
  (void)in_sizes; (void)n_in; (void)out_size; (void)ws_size;
  const int*   input = (const int*)d_in[0];
  const float* emb   = (const float*)d_in[1];
  const float* eWih  = (const float*)d_in[2];
  const float* eWhh  = (const float*)d_in[3];
  const float* ebih  = (const float*)d_in[4];
  const float* ebhh  = (const float*)d_in[5];
  /* d_in[6] dec_Wih unused: decoder input is always zero */
  const float* dWhh  = (const float*)d_in[7];
  const float* dbih  = (const float*)d_in[8];
  const float* dbhh  = (const float*)d_in[9];
  const float* W1    = (const float*)d_in[10];
  const float* W2    = (const float*)d_in[11];
  const float* vt    = (const float*)d_in[12];
  float* outF = (float*)d_out;

  float* wsf = (float*)d_ws;
  size_t o = 0;
  float* WgE   = wsf + o; o += (size_t)512 * 512 * 4;   // 4 MB
  float* WgD   = wsf + o; o += (size_t)512 * 512 * 4;   // 4 MB
  float* encInP = wsf + o; o += (size_t)Vsz * 2048;
  float* dbiasP = wsf + o; o += 2048;
  float* W1T  = wsf + o; o += (size_t)512 * 256;
  float* W2T  = wsf + o; o += (size_t)512 * 256;
  float* hTa  = wsf + o; o += (size_t)Hsz * Bsz;
  float* hTb  = wsf + o; o += (size_t)Hsz * Bsz;
  float* cET  = wsf + o; o += (size_t)Hsz * Bsz;
  float* hdTa = wsf + o; o += (size_t)Hsz * Bsz;
  float* hdTb = wsf + o; o += (size_t)Hsz * Bsz;
  float* cDT  = wsf + o; o += (size_t)Hsz * Bsz;
  float* b1   = wsf + o; o += (size_t)Bsz * Ssz * Wsz;
  unsigned long long* maskp = (unsigned long long*)(wsf + o); o += Bsz * 2;

  hipMemsetAsync(hTa, 0, (size_t)Hsz * Bsz * 4, stream);
  hipMemsetAsync(cET, 0, (size_t)Hsz * Bsz * 4, stream);
  hipMemsetAsync(hdTa, 0, (size_t)Hsz * Bsz * 4, stream);
  hipMemsetAsync(maskp, 0, (size_t)Bsz * 8, stream);

  prep_wgt<<<1024, 256, 0, stream>>>(eWhh, WgE);
  prep_wgt<<<1024, 256, 0, stream>>>(dWhh, WgD);
  prep_encin<<<(Vsz * 2048) / 4, 256, 0, stream>>>(emb, eWih, ebih, ebhh, encInP);
  prep_dbias<<<8, 256, 0, stream>>>(dbih, dbhh, dbiasP);
  prep_wtT<<<512, 256, 0, stream>>>(W1, W1T);
  prep_wtT<<<512, 256, 0, stream>>>(W2, W2T);

  // host-side: step keys = jax.random.split(jax.random.key(42), 50)
  unsigned kAh[Lsz], kBh[Lsz];
  for (int k = 0; k < Lsz; ++k)
    threefry2x32_hd(0u, 42u, 0u, (unsigned)k, kAh[k], kBh[k]);

  // encoder: step t computes h_{t+1}; fused blend1 handles hin = h_t (row t-1)
  float* hr = hTa; float* hw = hTb;
  for (int t = 0; t < Ssz; ++t) {
    float* b1row = (t >= 1) ? (b1 + (size_t)(t - 1) * Wsz) : nullptr;
    gates_fused<<<1024, 256, 0, stream>>>(hr, WgE, encInP, input, t, hw, cET,
                                          W1T, b1row);
    float* tp = hr; hr = hw; hw = tp;
  }
  blend1_row<<<512, 256, 0, stream>>>(hr, W1T, b1);  // h_50 -> row 49

  // decoder init: c0 = last encoder h (same [k][b] layout), h0 = 0
  hipMemcpyAsync(cDT, hr, (size_t)Hsz * Bsz * 4, hipMemcpyDeviceToDevice, stream);

  float* dr = hdTa; float* dw = hdTb;
  for (int k = 0; k < Lsz; ++k) {
    gates_fused<<<1024, 256, 0, stream>>>(dr, WgD, dbiasP, nullptr, 0, dw, cDT,
                                          nullptr, nullptr);
    scores_fused<<<1024, 256, 0, stream>>>(dw, W2T, b1, vt, maskp, outF,
                                           outF + (size_t)Bsz * Lsz * Ssz,
                                           k, kAh[k], kBh[k]);
    float* tp = dr; dr = dw; dw = tp;
  }
}

// Round 5
// 15414.462 us; speedup vs baseline: 1.4867x; 1.4420x over previous
//
#include <hip/hip_runtime.h>
#include <cstdint>

// Problem constants
#define Bsz 2048
#define Ssz 50
#define Esz 256
#define Hsz 512
#define Wsz 256
#define Lsz 50
#define Vsz 51

// ---------------- threefry2x32 (20 rounds), key words (k0,k1) ----------------
__host__ __device__ __forceinline__ void threefry2x32_hd(
    unsigned k0, unsigned k1, unsigned x0, unsigned x1,
    unsigned& o0, unsigned& o1) {
  unsigned ks2 = k0 ^ k1 ^ 0x1BD11BDAu;
  x0 += k0; x1 += k1;
#define TF_RND(r) { x0 += x1; x1 = (x1 << (r)) | (x1 >> (32 - (r))); x1 ^= x0; }
  TF_RND(13) TF_RND(15) TF_RND(26) TF_RND(6)
  x0 += k1; x1 += ks2 + 1u;
  TF_RND(17) TF_RND(29) TF_RND(16) TF_RND(24)
  x0 += ks2; x1 += k0 + 2u;
  TF_RND(13) TF_RND(15) TF_RND(26) TF_RND(6)
  x0 += k0; x1 += k1 + 3u;
  TF_RND(17) TF_RND(29) TF_RND(16) TF_RND(24)
  x0 += k1; x1 += ks2 + 4u;
  TF_RND(13) TF_RND(15) TF_RND(26) TF_RND(6)
  x0 += ks2; x1 += k0 + 5u;
#undef TF_RND
  o0 = x0; o1 = x1;
}

// ---- prep: WcombE[k][jq] f4: jq<512 -> enc Whh gate-quad, jq>=512 -> W1 quad -
__global__ __launch_bounds__(256) void prep_wcombE(
    const float* __restrict__ whh, const float* __restrict__ w1,
    float* __restrict__ dst) {
  int idx = blockIdx.x * 256 + threadIdx.x;   // < 512*576
  int k = idx / 576, j = idx - k * 576;
  float4 v;
  if (j < 512) {
    v.x = whh[(size_t)(0 * 512 + j) * 512 + k];
    v.y = whh[(size_t)(1 * 512 + j) * 512 + k];
    v.z = whh[(size_t)(2 * 512 + j) * 512 + k];
    v.w = whh[(size_t)(3 * 512 + j) * 512 + k];
  } else {
    int q = j - 512;
    v.x = w1[(size_t)(4 * q + 0) * 512 + k];
    v.y = w1[(size_t)(4 * q + 1) * 512 + k];
    v.z = w1[(size_t)(4 * q + 2) * 512 + k];
    v.w = w1[(size_t)(4 * q + 3) * 512 + k];
  }
  ((float4*)dst)[idx] = v;
}

// ------- prep: WgT[k][j] f4 = Whh[g*512+j][k]  (decoder, NCOL=512) ----------
__global__ __launch_bounds__(256) void prep_wgt(const float* __restrict__ src,
                                                float* __restrict__ dst) {
  int idx = blockIdx.x * 256 + threadIdx.x;   // < 512*512
  int j = idx & 511, k = idx >> 9;
  float4 v;
  v.x = src[(size_t)(0 * 512 + j) * 512 + k];
  v.y = src[(size_t)(1 * 512 + j) * 512 + k];
  v.z = src[(size_t)(2 * 512 + j) * 512 + k];
  v.w = src[(size_t)(3 * 512 + j) * 512 + k];
  ((float4*)dst)[(size_t)k * 512 + j] = v;
}

// ------- prep: WtT[k][w] = Wsrc[w][k]   (scalar float, [k][w]) --------------
__global__ __launch_bounds__(256) void prep_wtT(const float* __restrict__ src,
                                                float* __restrict__ dst) {
  int idx = blockIdx.x * 256 + threadIdx.x;   // < 512*256
  int w = idx & 255, k = idx >> 8;
  dst[(size_t)k * 256 + w] = src[(size_t)w * Hsz + k];
}

// ---------------- prep: encInP[v][j][g] = emb[v].Wih[g*512+j] + bih + bhh ----
__global__ __launch_bounds__(256) void prep_encin(
    const float* __restrict__ emb, const float* __restrict__ Wih,
    const float* __restrict__ bih, const float* __restrict__ bhh,
    float* __restrict__ encInP) {
  int wid = blockIdx.x * 4 + (threadIdx.x >> 6);
  int lane = threadIdx.x & 63;
  if (wid >= Vsz * 2048) return;
  int v = wid >> 11, col = wid & 2047;
  float4 e = ((const float4*)emb)[v * 64 + lane];
  float4 w = ((const float4*)Wih)[col * 64 + lane];
  float d = e.x * w.x + e.y * w.y + e.z * w.z + e.w * w.w;
  for (int off = 32; off; off >>= 1) d += __shfl_xor(d, off);
  if (lane == 0) {
    int g = col >> 9, j = col & 511;
    encInP[(size_t)v * 2048 + j * 4 + g] = d + bih[col] + bhh[col];
  }
}

// ---------------- prep: dbiasP[j][g] = dec_bih + dec_bhh ----------------
__global__ __launch_bounds__(256) void prep_dbias(const float* __restrict__ a,
                                                  const float* __restrict__ b,
                                                  float* __restrict__ dst) {
  int col = blockIdx.x * 256 + threadIdx.x;  // < 2048
  int g = col >> 9, j = col & 511;
  dst[j * 4 + g] = a[col] + b[col];
}

__device__ __forceinline__ void fma4(float4& a, float s, const float4& w) {
  a.x = fmaf(s, w.x, a.x);
  a.y = fmaf(s, w.y, a.y);
  a.z = fmaf(s, w.z, a.z);
  a.w = fmaf(s, w.w, a.w);
}

// ---------------- gates: register-pipelined streaming GEMM + LSTM -----------
// Block = 64 b x 32 jq; thread = 8 b x 1 jq (32 FMA/k). Wave: lanes -> 32
// consecutive jq (W coalesced 512B) x 2 b-octs (h wave-uniform f4 pairs).
// Explicit 2x4-k register double buffer: prefetch slack = 256 SIMD-cyc.
// NCOL=576 (enc: cols 512..575 = W1 -> blend1 of hin), NCOL=512 (dec).
template <int NCOL>
__global__ __launch_bounds__(256) void gates_fused(
    const float* __restrict__ hT, const float4* __restrict__ Wc, int jgrpBase,
    const float* __restrict__ addtab, const int* __restrict__ input, int tstep,
    float* __restrict__ houtT, float* __restrict__ cT,
    float* __restrict__ blendOut, int blendStride) {
  const int t = threadIdx.x;
  const int tjq = t & 31, tb = t >> 5;
  const int bgrp = blockIdx.x & 31;
  const int jgrp = (blockIdx.x >> 5) + jgrpBase;
  const int jq = jgrp * 32 + tjq;
  const int b0 = bgrp * 64 + tb * 8;

  const float4* __restrict__ Wr = Wc + jq;                       // + k*NCOL
  const float4* __restrict__ Hp = (const float4*)hT + (b0 >> 2); // + k*512

  float4 acc[8];
#pragma unroll
  for (int i = 0; i < 8; ++i) acc[i] = make_float4(0.f, 0.f, 0.f, 0.f);

  float4 wb0[4], wb1[4], hb0[8], hb1[8];
#pragma unroll
  for (int u = 0; u < 4; ++u) {
    wb0[u] = Wr[u * NCOL];
    hb0[2 * u] = Hp[u * 512];
    hb0[2 * u + 1] = Hp[u * 512 + 1];
  }

#define COMPUTE(WB, HB)                                        \
  _Pragma("unroll") for (int u = 0; u < 4; ++u) {              \
    float4 w = WB[u];                                          \
    float4 ha = HB[2 * u], hc = HB[2 * u + 1];                 \
    fma4(acc[0], ha.x, w); fma4(acc[1], ha.y, w);              \
    fma4(acc[2], ha.z, w); fma4(acc[3], ha.w, w);              \
    fma4(acc[4], hc.x, w); fma4(acc[5], hc.y, w);              \
    fma4(acc[6], hc.z, w); fma4(acc[7], hc.w, w);              \
  }
#define PREFETCH(WB, HB, KO)                                   \
  _Pragma("unroll") for (int u = 0; u < 4; ++u) {              \
    int ko = (KO) + u;                                         \
    WB[u] = Wr[ko * NCOL];                                     \
    HB[2 * u] = Hp[ko * 512];                                  \
    HB[2 * u + 1] = Hp[ko * 512 + 1];                          \
  }

#pragma unroll 1
  for (int kc = 0; kc < Hsz; kc += 8) {
    PREFETCH(wb1, hb1, kc + 4)
    COMPUTE(wb0, hb0)
    if (kc + 8 < Hsz) { PREFETCH(wb0, hb0, kc + 8) }
    COMPUTE(wb1, hb1)
  }
#undef COMPUTE
#undef PREFETCH

  if (NCOL == 512 || jq < 512) {
    // ---- LSTM epilogue ----
    int tok[8];
#pragma unroll
    for (int i = 0; i < 8; ++i)
      tok[i] = input ? input[(size_t)(b0 + i) * Ssz + tstep] : 0;
    float4 c0 = *(float4*)(cT + (size_t)jq * 2048 + b0);
    float4 c1 = *(float4*)(cT + (size_t)jq * 2048 + b0 + 4);
    float4 h0, h1;
    float* cp0 = &c0.x; float* cp1 = &c1.x;
    float* hp0 = &h0.x; float* hp1 = &h1.x;
#pragma unroll
    for (int i = 0; i < 8; ++i) {
      float4 av = ((const float4*)addtab)[(size_t)tok[i] * 512 + jq];
      float4 a = acc[i];
      float gi = a.x + av.x;
      float gf = a.y + av.y;
      float gg = a.z + av.z;
      float go = a.w + av.w;
      float si = 1.0f / (1.0f + expf(-gi));
      float sf = 1.0f / (1.0f + expf(-gf));
      float sg = tanhf(gg);
      float so = 1.0f / (1.0f + expf(-go));
      float cold = (i < 4) ? cp0[i] : cp1[i - 4];
      float cn = sf * cold + si * sg;
      float hn = so * tanhf(cn);
      if (i < 4) { cp0[i] = cn; hp0[i] = hn; }
      else       { cp1[i - 4] = cn; hp1[i - 4] = hn; }
    }
    *(float4*)(cT + (size_t)jq * 2048 + b0) = c0;
    *(float4*)(cT + (size_t)jq * 2048 + b0 + 4) = c1;
    *(float4*)(houtT + (size_t)jq * 2048 + b0) = h0;
    *(float4*)(houtT + (size_t)jq * 2048 + b0 + 4) = h1;
  } else if (blendOut != nullptr) {
    // ---- blend columns: store 4 w's per thread for 8 b rows ----
    const int w0 = (jq - 512) * 4;
#pragma unroll
    for (int i = 0; i < 8; ++i)
      *(float4*)(blendOut + (size_t)(b0 + i) * blendStride + w0) = acc[i];
  }
}

// ------- decoder fused: blend2 (phase A) + scores + log_softmax + sample -----
// grid 256 x 512 threads: 8 b per block.
__global__ __launch_bounds__(512) void scores_fused(
    const float* __restrict__ hdT, const float* __restrict__ W2T,
    const float* __restrict__ b1, const float* __restrict__ vt,
    unsigned long long* __restrict__ mask,
    float* __restrict__ probs, float* __restrict__ tour,
    int stepk, unsigned kA, unsigned kB) {
  __shared__ float b2s[8][256];
  __shared__ float vts[256];
  __shared__ float sc[8][64];
  const int t = threadIdx.x;
  const int b0 = blockIdx.x * 8;

  // ---- phase A: blend2 for 8 b; thread = 1 w x 4 b ----
  {
    const int w = t & 255, bh = t >> 8;  // bh 0/1
    const float* __restrict__ hp = hdT + b0 + bh * 4;
    float a[4] = {0.f, 0.f, 0.f, 0.f};
#pragma unroll 8
    for (int kk = 0; kk < Hsz; ++kk) {
      float wv = W2T[(size_t)kk * 256 + w];
      float4 hv = *(const float4*)(hp + (size_t)kk * 2048);
      a[0] = fmaf(hv.x, wv, a[0]);
      a[1] = fmaf(hv.y, wv, a[1]);
      a[2] = fmaf(hv.z, wv, a[2]);
      a[3] = fmaf(hv.w, wv, a[3]);
    }
#pragma unroll
    for (int i = 0; i < 4; ++i) b2s[bh * 4 + i][w] = a[i];
    if (t < 256) vts[t] = vt[t];
  }
  __syncthreads();

  // ---- phase B: scores rows (8 b x 50 s), one wave per row ----
  const int wave = t >> 6, lane = t & 63;
  for (int r = wave; r < 8 * Ssz; r += 8) {
    const int b = r / Ssz, s = r - b * Ssz;
    const float4* row = (const float4*)(b1 + ((size_t)(b0 + b) * Ssz + s) * Wsz);
    float4 rv = row[lane];
    float4 bv = *(const float4*)&b2s[b][lane * 4];
    float4 vv = *(const float4*)&vts[lane * 4];
    float v = vv.x * tanhf(rv.x + bv.x) + vv.y * tanhf(rv.y + bv.y) +
              vv.z * tanhf(rv.z + bv.z) + vv.w * tanhf(rv.w + bv.w);
    for (int off = 32; off; off >>= 1) v += __shfl_xor(v, off);
    if (lane == 0) sc[b][s] = v;
  }
  __syncthreads();

  // ---- phase C: mask, log_softmax, gumbel sample, mask update (wave = b) ----
  {
    const int gb = b0 + wave;
    unsigned long long m = mask[gb];
    float x = (lane < Ssz) ? sc[wave][lane] : -INFINITY;
    if (lane < Ssz && ((m >> lane) & 1ull)) x = -100000.0f;
    float mv = x;
    for (int off = 32; off; off >>= 1) mv = fmaxf(mv, __shfl_xor(mv, off));
    float sh = x - mv;
    float e = (lane < Ssz) ? expf(sh) : 0.f;
    float ssum = e;
    for (int off = 32; off; off >>= 1) ssum += __shfl_xor(ssum, off);
    float lg = logf(ssum);
    float logp = sh - lg;
    if (lane < Ssz) probs[(size_t)gb * (Lsz * Ssz) + stepk * Ssz + lane] = logp;

    float val = -INFINITY;
    if (lane < Ssz) {
      unsigned j = (unsigned)(gb * Ssz + lane);
      unsigned o0, o1;
      threefry2x32_hd(kA, kB, 0u, j, o0, o1);
      unsigned bits = o0 ^ o1;
      float f = __uint_as_float((bits >> 9) | 0x3F800000u) - 1.0f;
      float u = fmaxf(1.17549435e-38f, f + 1.17549435e-38f);
      val = logp - logf(-logf(u));
    }
    int idx = lane;
    for (int off = 32; off; off >>= 1) {
      float ov = __shfl_xor(val, off);
      int oi = __shfl_xor(idx, off);
      if (ov > val || (ov == val && oi < idx)) { val = ov; idx = oi; }
    }
    if (lane == 0) {
      tour[(size_t)gb * Lsz + stepk] = (float)idx;
      mask[gb] = m | (1ull << idx);
    }
  }
}

extern "C" void kernel_launch(void* const* d_in, const int* in_sizes, int n_in,
                              void* d_out, int out_size, void* d_ws, size_t ws_size,
                              hipStream_t stream) {
  (void)in_sizes; (void)n_in; (void)out_size; (void)ws_size;
  const int*   input = (const int*)d_in[0];
  const float* emb   = (const float*)d_in[1];
  const float* eWih  = (const float*)d_in[2];
  const float* eWhh  = (const float*)d_in[3];
  const float* ebih  = (const float*)d_in[4];
  const float* ebhh  = (const float*)d_in[5];
  /* d_in[6] dec_Wih unused: decoder input is always zero */
  const float* dWhh  = (const float*)d_in[7];
  const float* dbih  = (const float*)d_in[8];
  const float* dbhh  = (const float*)d_in[9];
  const float* W1    = (const float*)d_in[10];
  const float* W2    = (const float*)d_in[11];
  const float* vt    = (const float*)d_in[12];
  float* outF = (float*)d_out;

  float* wsf = (float*)d_ws;
  size_t o = 0;
  float* WcE   = wsf + o; o += (size_t)512 * 576 * 4;   // 4.7 MB
  float* WgD   = wsf + o; o += (size_t)512 * 512 * 4;   // 4.2 MB
  float* encInP = wsf + o; o += (size_t)Vsz * 2048;
  float* dbiasP = wsf + o; o += 2048;
  float* W2T  = wsf + o; o += (size_t)512 * 256;
  float* hTa  = wsf + o; o += (size_t)Hsz * Bsz;
  float* hTb  = wsf + o; o += (size_t)Hsz * Bsz;
  float* cET  = wsf + o; o += (size_t)Hsz * Bsz;
  float* hdTa = wsf + o; o += (size_t)Hsz * Bsz;
  float* hdTb = wsf + o; o += (size_t)Hsz * Bsz;
  float* cDT  = wsf + o; o += (size_t)Hsz * Bsz;
  float* b1   = wsf + o; o += (size_t)Bsz * Ssz * Wsz;
  unsigned long long* maskp = (unsigned long long*)(wsf + o); o += Bsz * 2;

  hipMemsetAsync(hTa, 0, (size_t)Hsz * Bsz * 4, stream);
  hipMemsetAsync(cET, 0, (size_t)Hsz * Bsz * 4, stream);
  hipMemsetAsync(hdTa, 0, (size_t)Hsz * Bsz * 4, stream);
  hipMemsetAsync(maskp, 0, (size_t)Bsz * 8, stream);

  prep_wcombE<<<1152, 256, 0, stream>>>(eWhh, W1, WcE);
  prep_wgt<<<1024, 256, 0, stream>>>(dWhh, WgD);
  prep_encin<<<(Vsz * 2048) / 4, 256, 0, stream>>>(emb, eWih, ebih, ebhh, encInP);
  prep_dbias<<<8, 256, 0, stream>>>(dbih, dbhh, dbiasP);
  prep_wtT<<<512, 256, 0, stream>>>(W2, W2T);

  // host-side: step keys = jax.random.split(jax.random.key(42), 50)
  unsigned kAh[Lsz], kBh[Lsz];
  for (int k = 0; k < Lsz; ++k)
    threefry2x32_hd(0u, 42u, 0u, (unsigned)k, kAh[k], kBh[k]);

  const int b1Stride = Ssz * Wsz;

  // encoder: step t computes h_{t+1}; fused W1 cols emit blend1(h_t) -> row t-1
  float* hr = hTa; float* hw = hTb;
  for (int t = 0; t < Ssz; ++t) {
    float* b1row = (t >= 1) ? (b1 + (size_t)(t - 1) * Wsz) : nullptr;
    gates_fused<576><<<576, 256, 0, stream>>>(
        hr, (const float4*)WcE, 0, encInP, input, t, hw, cET, b1row, b1Stride);
    float* tp = hr; hr = hw; hw = tp;
  }
  // tail: blend1(h_50) -> row 49 (blend-only launch: jgrp 16..17)
  gates_fused<576><<<64, 256, 0, stream>>>(
      hr, (const float4*)WcE, 16, encInP, nullptr, 0, hTb, cET,
      b1 + (size_t)(Ssz - 1) * Wsz, b1Stride);

  // decoder init: c0 = last encoder h (same [k][b] layout), h0 = 0
  hipMemcpyAsync(cDT, hr, (size_t)Hsz * Bsz * 4, hipMemcpyDeviceToDevice, stream);

  float* dr = hdTa; float* dw = hdTb;
  for (int k = 0; k < Lsz; ++k) {
    gates_fused<512><<<512, 256, 0, stream>>>(
        dr, (const float4*)WgD, 0, dbiasP, nullptr, 0, dw, cDT, nullptr, 0);
    scores_fused<<<256, 512, 0, stream>>>(dw, W2T, b1, vt, maskp, outF,
                                          outF + (size_t)Bsz * Lsz * Ssz,
                                          k, kAh[k], kBh[k]);
    float* tp = dr; dr = dw; dw = tp;
  }
}